// Round 5
// baseline (170.793 us; speedup 1.0000x reference)
//
#include <hip/hip_runtime.h>
#include <stdint.h>

// DBMLLoss on MI355X — round 5: symmetric (triangular) sim computation.
// feats: [4096,512] f32 (L2-normalized rows), labels: [4096] i32, out: scalar f32.
// sim = F F^T is symmetric: compute only tiles bi<=bj; off-diagonal tiles fold into
// row-stats of panel bi AND col-stats (== row-stats of panel bj via transpose).
// Partials: 32 slots per row; row-panel p gets slot j from block (p,j>=p) row-fold
// and slot i from block (i<p,p) col-fold — complete & disjoint.

#define Bn 4096
#define Dk 512
#define BM 128            // tile rows
#define TBN 128           // tile cols
#define BK 64             // K step
#define NSTEP 8           // Dk/BK
#define NSLOT 32
#define ONE_EPS 0.99999f  // 1 - 1e-5

typedef short bf16x8 __attribute__((ext_vector_type(8)));
typedef float f32x4 __attribute__((ext_vector_type(4)));

__device__ __forceinline__ unsigned short f2bf(float x) {
  unsigned int u = __float_as_uint(x);
  u += 0x7fffu + ((u >> 16) & 1u);   // RNE
  return (unsigned short)(u >> 16);
}

// featT layout: [kb 0..63][row 0..4095][8 bf16]  (kb = k/8)
__global__ __launch_bounds__(256) void convert_kernel(const float* __restrict__ feats,
                                                      unsigned short* __restrict__ featT) {
  int g = blockIdx.x * 256 + threadIdx.x;  // g = kb*4096 + row
  int row = g & 4095;
  int kb = g >> 12;
  const float* src = feats + (size_t)row * Dk + kb * 8;
  f32x4 f0 = *(const f32x4*)(src);
  f32x4 f1 = *(const f32x4*)(src + 4);
  union { unsigned short u[8]; bf16x8 v; } o;
  o.u[0] = f2bf(f0[0]); o.u[1] = f2bf(f0[1]); o.u[2] = f2bf(f0[2]); o.u[3] = f2bf(f0[3]);
  o.u[4] = f2bf(f1[0]); o.u[5] = f2bf(f1[1]); o.u[6] = f2bf(f1[2]); o.u[7] = f2bf(f1[3]);
  *(bf16x8*)(featT + (size_t)g * 8) = o.v;
}

__device__ __forceinline__ void gload16(const unsigned short* g, short* l) {
  __builtin_amdgcn_global_load_lds((const __attribute__((address_space(1))) unsigned int*)g,
                                   (__attribute__((address_space(3))) unsigned int*)l,
                                   16, 0, 0);
}

// PHASE 1 stats (5): sum, sumsq, max_neg, min_pos, pos_cnt
// PHASE 2 stats (6): n_pos, n_neg, sum_sel, sumsq_sel, fp_sum, fn_sum
template <int PHASE>
__global__ __launch_bounds__(512, 2) void phase_kernel(const unsigned short* __restrict__ featT,
                                                       const int* __restrict__ labels,
                                                       const float* __restrict__ rs,
                                                       float* __restrict__ part) {
  // double-buffered LDS tiles, k-outer: [kb 0..7][r 0..127][8 bf16]
  __shared__ short As[2][8192];
  __shared__ short Bs[2][8192];
  __shared__ int rl[BM];
  __shared__ int cl[TBN];

  const int tid = threadIdx.x;
  const int lane = tid & 63;
  const int wid = tid >> 6;
  const int WR = wid & 3;    // 4 row groups of 32
  const int WC = wid >> 2;   // 2 col groups of 64
  const int l15 = lane & 15;
  const int l4 = lane >> 4;

  // ---- triangular tile decode: t -> (bi, bj), bi <= bj ----
  const int t = blockIdx.x;
  int bi = (int)floorf((65.0f - sqrtf(4225.0f - 8.0f * (float)t)) * 0.5f);
  int Ci = bi * (65 - bi) / 2;
  if (Ci > t) { --bi; Ci = bi * (65 - bi) / 2; }
  else { int Cn = (bi + 1) * (64 - bi) / 2; if (Cn <= t) { ++bi; Ci = Cn; } }
  const int bj = bi + (t - Ci);
  const int row0 = bi * BM;
  const int col0 = bj * TBN;
  const bool isdiag = (bi == bj);

  if (tid < BM) rl[tid] = labels[row0 + tid];
  else if (tid < BM + TBN) cl[tid - BM] = labels[col0 + tid - BM];

  int rowl[2][4], rlab[2][4];
#pragma unroll
  for (int m = 0; m < 2; ++m)
#pragma unroll
    for (int r = 0; r < 4; ++r) {
      rowl[m][r] = WR * 32 + m * 16 + l4 * 4 + r;  // C/D: row=(l>>4)*4+reg
      rlab[m][r] = 0;
    }

  // stage step s (kt = s) into buf s&1
  auto stage = [&](int s) {
    const int kt = s, bb = s & 1;
#pragma unroll
    for (int i = 0; i < 2; ++i) {
      const int q = tid + i * 512;
      const int r = q & 127;
      const int kb = q >> 7;
      const int ko = (kt * 8 + kb) * (Bn * 8);
      gload16(featT + ko + (row0 + r) * 8, &As[bb][q * 8]);
      gload16(featT + ko + (col0 + r) * 8, &Bs[bb][q * 8]);
    }
  };

  stage(0);

  f32x4 acc[2][4];
#pragma unroll
  for (int m = 0; m < 2; ++m)
#pragma unroll
    for (int n = 0; n < 4; ++n) acc[m][n] = (f32x4){0.f, 0.f, 0.f, 0.f};

  for (int s = 0; s < NSTEP; ++s) {
    __syncthreads();  // drains stage(s) (issued a compute phase ago) + publishes
    if (s + 1 < NSTEP) stage(s + 1);
    if (s == 0) {  // labels visible now
#pragma unroll
      for (int m = 0; m < 2; ++m)
#pragma unroll
        for (int r = 0; r < 4; ++r) rlab[m][r] = rl[rowl[m][r]];
    }
    const int bb = s & 1;
#pragma unroll
    for (int ks = 0; ks < 2; ++ks) {
      const int kb = ks * 4 + l4;
      bf16x8 af[2], bf[4];
#pragma unroll
      for (int m = 0; m < 2; ++m)
        af[m] = *(const bf16x8*)&As[bb][(kb * 128 + WR * 32 + m * 16 + l15) * 8];
#pragma unroll
      for (int n = 0; n < 4; ++n)
        bf[n] = *(const bf16x8*)&Bs[bb][(kb * 128 + WC * 64 + n * 16 + l15) * 8];
#pragma unroll
      for (int m = 0; m < 2; ++m)
#pragma unroll
        for (int n = 0; n < 4; ++n)
          acc[m][n] = __builtin_amdgcn_mfma_f32_16x16x32_bf16(af[m], bf[n], acc[m][n], 0, 0, 0);
    }
  }

  __syncthreads();  // LDS tiles no longer needed; As becomes float scratch
  float* mbuf2 = (float*)&As[0][0];       // col merge: [WR 0..3][col 0..127][6] = 12 KB
  float* mbuf = mbuf2 + 4 * 128 * 6;      // row WC-merge: [row 0..127][6] = 3 KB

  // thresholds (phase 2)
  float thrp[2][4], thrn[2][4], thrpc[4], thrnc[4];
  if constexpr (PHASE == 2) {
#pragma unroll
    for (int m = 0; m < 2; ++m)
#pragma unroll
      for (int r = 0; r < 4; ++r) {
        thrp[m][r] = rs[2 * Bn + row0 + rowl[m][r]];  // max_neg (row)
        thrn[m][r] = rs[3 * Bn + row0 + rowl[m][r]];  // min_pos (row)
      }
#pragma unroll
    for (int n = 0; n < 4; ++n) {
      int lc = WC * 64 + n * 16 + l15;
      thrpc[n] = rs[2 * Bn + col0 + lc];
      thrnc[n] = rs[3 * Bn + col0 + lc];
    }
  }

  // row stats
  float s0[2][4], s1[2][4], s2[2][4], s3[2][4], s4[2][4], s5[2][4];
#pragma unroll
  for (int m = 0; m < 2; ++m)
#pragma unroll
    for (int r = 0; r < 4; ++r) {
      s0[m][r] = 0.f; s1[m][r] = 0.f;
      s2[m][r] = (PHASE == 1) ? -__builtin_inff() : 0.f;
      s3[m][r] = (PHASE == 1) ? __builtin_inff() : 0.f;
      s4[m][r] = 0.f; s5[m][r] = 0.f;
    }

  // ---- fold: per-n col transients reduced & stashed immediately ----
#pragma unroll
  for (int n = 0; n < 4; ++n) {
    const int lcolt = WC * 64 + n * 16 + l15;
    const int clab = cl[lcolt];
    float c0 = 0.f, c1 = 0.f, c4 = 0.f, c5 = 0.f;
    float c2 = (PHASE == 1) ? -__builtin_inff() : 0.f;
    float c3 = (PHASE == 1) ? __builtin_inff() : 0.f;
#pragma unroll
    for (int m = 0; m < 2; ++m)
#pragma unroll
      for (int r = 0; r < 4; ++r) {
        float s = acc[m][n][r];
        if (isdiag && (lcolt == rowl[m][r])) s = 1.0f;  // exact self-sim
        bool same = (rlab[m][r] == clab);
        if constexpr (PHASE == 1) {
          s0[m][r] += s;
          s1[m][r] += s * s;
          if (!same) s2[m][r] = fmaxf(s2[m][r], s);
          else if (s < ONE_EPS) { s3[m][r] = fminf(s3[m][r], s); s4[m][r] += 1.0f; }
          if (!isdiag) {
            c0 += s; c1 += s * s;
            if (!same) c2 = fmaxf(c2, s);
            else if (s < ONE_EPS) { c3 = fminf(c3, s); c4 += 1.0f; }
          }
        } else {
          float ep = __expf(2.0f - 2.0f * s);
          float en = __expf(2.0f * s - 1.2f);
          bool pr = same && (s < ONE_EPS) && (s - 0.1f < thrp[m][r]);
          bool nr = (!same) && (s + 0.1f > thrn[m][r]);
          if (pr) { s0[m][r] += 1.0f; s4[m][r] += ep; }
          if (nr) { s1[m][r] += 1.0f; s5[m][r] += en; }
          if (pr || nr) { s2[m][r] += s; s3[m][r] += s * s; }
          if (!isdiag) {
            bool pc = same && (s < ONE_EPS) && (s - 0.1f < thrpc[n]);
            bool nc = (!same) && (s + 0.1f > thrnc[n]);
            if (pc) { c0 += 1.0f; c4 += ep; }
            if (nc) { c1 += 1.0f; c5 += en; }
            if (pc || nc) { c2 += s; c3 += s * s; }
          }
        }
      }
    if (!isdiag) {
      // reduce across the 4 l4-groups (rows) of this wave
#pragma unroll
      for (int d = 16; d < 64; d <<= 1) {
        c0 += __shfl_xor(c0, d);
        c1 += __shfl_xor(c1, d);
        if constexpr (PHASE == 1) {
          c2 = fmaxf(c2, __shfl_xor(c2, d));
          c3 = fminf(c3, __shfl_xor(c3, d));
        } else {
          c2 += __shfl_xor(c2, d);
          c3 += __shfl_xor(c3, d);
          c5 += __shfl_xor(c5, d);
        }
        c4 += __shfl_xor(c4, d);
      }
      if (l4 == 0) {
        float* p = &mbuf2[(WR * 128 + lcolt) * 6];
        p[0] = c0; p[1] = c1; p[2] = c2; p[3] = c3; p[4] = c4;
        if constexpr (PHASE == 2) p[5] = c5;
      }
    }
  }

  // row butterfly across the 16 lanes (different cols, same rows)
#pragma unroll
  for (int d = 1; d < 16; d <<= 1) {
#pragma unroll
    for (int m = 0; m < 2; ++m)
#pragma unroll
      for (int r = 0; r < 4; ++r) {
        s0[m][r] += __shfl_xor(s0[m][r], d);
        s1[m][r] += __shfl_xor(s1[m][r], d);
        if constexpr (PHASE == 1) {
          s2[m][r] = fmaxf(s2[m][r], __shfl_xor(s2[m][r], d));
          s3[m][r] = fminf(s3[m][r], __shfl_xor(s3[m][r], d));
          s4[m][r] += __shfl_xor(s4[m][r], d);
        } else {
          s2[m][r] += __shfl_xor(s2[m][r], d);
          s3[m][r] += __shfl_xor(s3[m][r], d);
          s4[m][r] += __shfl_xor(s4[m][r], d);
          s5[m][r] += __shfl_xor(s5[m][r], d);
        }
      }
  }
  if (WC == 1 && l15 == 0) {
#pragma unroll
    for (int m = 0; m < 2; ++m)
#pragma unroll
      for (int r = 0; r < 4; ++r) {
        float* p = &mbuf[rowl[m][r] * 6];
        p[0] = s0[m][r]; p[1] = s1[m][r]; p[2] = s2[m][r];
        p[3] = s3[m][r]; p[4] = s4[m][r]; p[5] = s5[m][r];
      }
  }
  __syncthreads();

  // ---- row stats out (slot bj) ----
  if (WC == 0 && l15 == 0) {
#pragma unroll
    for (int m = 0; m < 2; ++m)
#pragma unroll
      for (int r = 0; r < 4; ++r) {
        int lr = rowl[m][r];
        int rowg = row0 + lr;
        const float* p = &mbuf[lr * 6];
        float t0 = s0[m][r] + p[0];
        float t1 = s1[m][r] + p[1];
        float t2, t3;
        if constexpr (PHASE == 1) {
          t2 = fmaxf(s2[m][r], p[2]);
          t3 = fminf(s3[m][r], p[3]);
        } else {
          t2 = s2[m][r] + p[2];
          t3 = s3[m][r] + p[3];
        }
        float t4 = s4[m][r] + p[4];
        part[(size_t)(0 * Bn + rowg) * NSLOT + bj] = t0;
        part[(size_t)(1 * Bn + rowg) * NSLOT + bj] = t1;
        part[(size_t)(2 * Bn + rowg) * NSLOT + bj] = t2;
        part[(size_t)(3 * Bn + rowg) * NSLOT + bj] = t3;
        part[(size_t)(4 * Bn + rowg) * NSLOT + bj] = t4;
        if constexpr (PHASE == 2)
          part[(size_t)(5 * Bn + rowg) * NSLOT + bj] = s5[m][r] + p[5];
      }
  }

  // ---- col stats out (slot bi), off-diagonal only ----
  if (!isdiag && tid < TBN) {
    const int c = tid;
    const float* p0 = &mbuf2[(0 * 128 + c) * 6];
    const float* p1 = &mbuf2[(1 * 128 + c) * 6];
    const float* p2 = &mbuf2[(2 * 128 + c) * 6];
    const float* p3 = &mbuf2[(3 * 128 + c) * 6];
    int colg = col0 + c;
    float v0 = p0[0] + p1[0] + p2[0] + p3[0];
    float v1 = p0[1] + p1[1] + p2[1] + p3[1];
    float v2, v3;
    if constexpr (PHASE == 1) {
      v2 = fmaxf(fmaxf(p0[2], p1[2]), fmaxf(p2[2], p3[2]));
      v3 = fminf(fminf(p0[3], p1[3]), fminf(p2[3], p3[3]));
    } else {
      v2 = p0[2] + p1[2] + p2[2] + p3[2];
      v3 = p0[3] + p1[3] + p2[3] + p3[3];
    }
    float v4 = p0[4] + p1[4] + p2[4] + p3[4];
    part[(size_t)(0 * Bn + colg) * NSLOT + bi] = v0;
    part[(size_t)(1 * Bn + colg) * NSLOT + bi] = v1;
    part[(size_t)(2 * Bn + colg) * NSLOT + bi] = v2;
    part[(size_t)(3 * Bn + colg) * NSLOT + bi] = v3;
    part[(size_t)(4 * Bn + colg) * NSLOT + bi] = v4;
    if constexpr (PHASE == 2)
      part[(size_t)(5 * Bn + colg) * NSLOT + bi] = p0[5] + p1[5] + p2[5] + p3[5];
  }
}

__global__ __launch_bounds__(256) void reduce1_kernel(const float* __restrict__ part,
                                                      float* __restrict__ rs) {
  int row = blockIdx.x * 256 + threadIdx.x;
  float sum = 0.f, ssq = 0.f, pc = 0.f;
  float mxn = -__builtin_inff(), mnp = __builtin_inff();
#pragma unroll
  for (int sl = 0; sl < NSLOT; ++sl) {
    sum += part[(size_t)(0 * Bn + row) * NSLOT + sl];
    ssq += part[(size_t)(1 * Bn + row) * NSLOT + sl];
    mxn = fmaxf(mxn, part[(size_t)(2 * Bn + row) * NSLOT + sl]);
    mnp = fminf(mnp, part[(size_t)(3 * Bn + row) * NSLOT + sl]);
    pc += part[(size_t)(4 * Bn + row) * NSLOT + sl];
  }
  rs[0 * Bn + row] = sum;
  rs[1 * Bn + row] = ssq;
  rs[2 * Bn + row] = mxn;
  rs[3 * Bn + row] = mnp;
  rs[4 * Bn + row] = pc;
}

__global__ __launch_bounds__(256) void finalize_kernel(const float* __restrict__ p2,
                                                       const float* __restrict__ rs,
                                                       float* __restrict__ out) {
  int tid = threadIdx.x;
  int row = blockIdx.x * 256 + tid;
  float np = 0.f, nn = 0.f, ssel = 0.f, qsel = 0.f, fp = 0.f, fn = 0.f;
#pragma unroll
  for (int sl = 0; sl < NSLOT; ++sl) {
    np += p2[(size_t)(0 * Bn + row) * NSLOT + sl];
    nn += p2[(size_t)(1 * Bn + row) * NSLOT + sl];
    ssel += p2[(size_t)(2 * Bn + row) * NSLOT + sl];
    qsel += p2[(size_t)(3 * Bn + row) * NSLOT + sl];
    fp += p2[(size_t)(4 * Bn + row) * NSLOT + sl];
    fn += p2[(size_t)(5 * Bn + row) * NSLOT + sl];
  }
  float sumall = rs[0 * Bn + row];
  float ssqall = rs[1 * Bn + row];
  float pc = rs[4 * Bn + row];

  float mean_all = sumall * (1.0f / Bn);
  float sigma_all = ssqall - (float)Bn * mean_all * mean_all;
  float cnt = fmaxf(np + nn, 1.0f);
  float mean_sel = ssel / cnt;
  float sigma_sel = qsel / cnt - mean_sel * mean_sel;
  float loss = __logf(1.0f + fp) + __logf(1.0f + fn) +
               0.5f * (fabsf(mean_all - mean_sel) + fabsf(sigma_all - sigma_sel));
  bool valid = (pc > 0.5f) && (pc < (float)(Bn - 1) - 0.5f) && (np > 0.5f) && (nn > 0.5f);
  float v = valid ? loss : 0.f;
#pragma unroll
  for (int d = 1; d < 64; d <<= 1) v += __shfl_xor(v, d);
  __shared__ float ls[4];
  if ((tid & 63) == 0) ls[tid >> 6] = v;
  __syncthreads();
  if (tid == 0) atomicAdd(out, (ls[0] + ls[1] + ls[2] + ls[3]) * (1.0f / (float)Bn));
}

extern "C" void kernel_launch(void* const* d_in, const int* in_sizes, int n_in,
                              void* d_out, int out_size, void* d_ws, size_t ws_size,
                              hipStream_t stream) {
  const float* feats = (const float*)d_in[0];
  const int* labels = (const int*)d_in[1];
  float* out = (float*)d_out;
  char* ws = (char*)d_ws;

  // ws layout (bytes):
  unsigned short* featT = (unsigned short*)(ws);        // 4,194,304
  float* part = (float*)(ws + 4194304);                 // 6*4096*32*4 = 3,145,728 (shared p1/p2)
  float* rs = (float*)(ws + 4194304 + 3145728);         // 5*4096*4   =    81,920

  hipMemsetAsync(d_out, 0, sizeof(float), stream);
  convert_kernel<<<1024, 256, 0, stream>>>(feats, featT);
  const int ntile = 32 * 33 / 2;  // 528 triangular tiles
  phase_kernel<1><<<ntile, 512, 0, stream>>>(featT, labels, nullptr, part);
  reduce1_kernel<<<Bn / 256, 256, 0, stream>>>(part, rs);
  phase_kernel<2><<<ntile, 512, 0, stream>>>(featT, labels, rs, part);
  finalize_kernel<<<Bn / 256, 256, 0, stream>>>(part, rs, out);
}

// Round 7
// 125.671 us; speedup vs baseline: 1.3590x; 1.3590x over previous
//
#include <hip/hip_runtime.h>
#include <stdint.h>

// DBMLLoss on MI355X — round 7: compute sim ONCE, materialize bf16 sim to ws.
// feats: [4096,512] f32 (L2-normalized rows), labels: [4096] i32, out: scalar f32.
// Path A (ws_size >= 39.1MB): phase1 = GEMM + pass-1 fold + bf16 sim write (simb[c][r],
//   valid since sim is symmetric). pass2 = streaming per-row fold from simb, fused with
//   the slot-reduce and the final loss/atomicAdd. 4 launches total.
// Path B (small ws): round-4 two-GEMM structure (verified 155us).

#define Bn 4096
#define Dk 512
#define NCHUNK 16         // col chunks; grid = 32 x 16 = 512 blocks
#define CWIDTH 256        // cols per chunk
#define BM 128            // rows per block
#define TBN 128           // cols per tile step
#define BK 64             // K step
#define NSTEP 16          // (CWIDTH/TBN) * (Dk/BK)
#define ONE_EPS 0.99999f  // 1 - 1e-5

typedef short bf16x8 __attribute__((ext_vector_type(8)));
typedef unsigned short u16x4 __attribute__((ext_vector_type(4)));
typedef float f32x4 __attribute__((ext_vector_type(4)));

__device__ __forceinline__ unsigned short f2bf(float x) {
  unsigned int u = __float_as_uint(x);
  u += 0x7fffu + ((u >> 16) & 1u);   // RNE
  return (unsigned short)(u >> 16);
}

// featT layout: [kb 0..63][row 0..4095][8 bf16]  (kb = k/8)
__global__ __launch_bounds__(256) void convert_kernel(const float* __restrict__ feats,
                                                      unsigned short* __restrict__ featT) {
  int g = blockIdx.x * 256 + threadIdx.x;  // g = kb*4096 + row
  int row = g & 4095;
  int kb = g >> 12;
  const float* src = feats + (size_t)row * Dk + kb * 8;
  f32x4 f0 = *(const f32x4*)(src);
  f32x4 f1 = *(const f32x4*)(src + 4);
  union { unsigned short u[8]; bf16x8 v; } o;
  o.u[0] = f2bf(f0[0]); o.u[1] = f2bf(f0[1]); o.u[2] = f2bf(f0[2]); o.u[3] = f2bf(f0[3]);
  o.u[4] = f2bf(f1[0]); o.u[5] = f2bf(f1[1]); o.u[6] = f2bf(f1[2]); o.u[7] = f2bf(f1[3]);
  *(bf16x8*)(featT + (size_t)g * 8) = o.v;
}

__device__ __forceinline__ void gload16(const unsigned short* g, short* l) {
  __builtin_amdgcn_global_load_lds((const __attribute__((address_space(1))) unsigned int*)g,
                                   (__attribute__((address_space(3))) unsigned int*)l,
                                   16, 0, 0);
}

// PHASE 1 partials (5): sum, sumsq, max_neg, min_pos, pos_cnt  (+ optional sim write)
// PHASE 2 partials (6): n_pos, n_neg, sum_sel, sumsq_sel, fp_sum, fn_sum (fallback only)
template <int PHASE, bool WSIM>
__global__ __launch_bounds__(512, 2) void phase_kernel(const unsigned short* __restrict__ featT,
                                                       const int* __restrict__ labels,
                                                       const float* __restrict__ rs,
                                                       float* __restrict__ part,
                                                       unsigned short* __restrict__ simb) {
  // double-buffered LDS tiles, k-outer: [kb 0..7][r 0..127][8 bf16]
  __shared__ short As[2][8192];
  __shared__ short Bs[2][8192];
  __shared__ int rl[BM];
  __shared__ int cl[CWIDTH];

  const int tid = threadIdx.x;
  const int wid = tid >> 6;
  const int lane = tid & 63;
  const int WR = wid & 3;    // 4 row groups of 32
  const int WC = wid >> 2;   // 2 col groups of 64
  const int l15 = lane & 15;
  const int l4 = lane >> 4;
  const int row0 = blockIdx.x * BM;
  const int chunk0 = blockIdx.y * CWIDTH;

  if (tid < BM) rl[tid] = labels[row0 + tid];
  if (tid < CWIDTH) cl[tid] = labels[chunk0 + tid];

  int rlab[2][4], rowl[2][4];
  float thrp[2][4], thrn[2][4];
#pragma unroll
  for (int m = 0; m < 2; ++m)
#pragma unroll
    for (int r = 0; r < 4; ++r) {
      int lr = WR * 32 + m * 16 + l4 * 4 + r;  // tile-local row (C/D: row=(l>>4)*4+reg)
      rowl[m][r] = lr;
      rlab[m][r] = 0;
      if constexpr (PHASE == 2) {
        thrp[m][r] = rs[2 * Bn + row0 + lr];  // max_neg
        thrn[m][r] = rs[3 * Bn + row0 + lr];  // min_pos
      }
    }

  float s0[2][4], s1[2][4], s2[2][4], s3[2][4], s4[2][4], s5[2][4];
#pragma unroll
  for (int m = 0; m < 2; ++m)
#pragma unroll
    for (int r = 0; r < 4; ++r) {
      s0[m][r] = 0.f; s1[m][r] = 0.f;
      s2[m][r] = (PHASE == 1) ? -__builtin_inff() : 0.f;
      s3[m][r] = (PHASE == 1) ? __builtin_inff() : 0.f;
      s4[m][r] = 0.f; s5[m][r] = 0.f;
    }

  // stage step s: A rows panel + B cols panel for (ct = s>>3, kt = s&7) into buf s&1
  auto stage = [&](int s) {
    const int ct = s >> 3, kt = s & 7, bb = s & 1;
    const int cbase = chunk0 + ct * TBN;
#pragma unroll
    for (int i = 0; i < 2; ++i) {
      const int q = tid + i * 512;
      const int r = q & 127;
      const int kb = q >> 7;
      const int ko = (kt * 8 + kb) * (Bn * 8);
      gload16(featT + ko + (row0 + r) * 8, &As[bb][q * 8]);
      gload16(featT + ko + (cbase + r) * 8, &Bs[bb][q * 8]);
    }
  };

  stage(0);

  for (int ct = 0; ct < CWIDTH / TBN; ++ct) {
    const int col0 = chunk0 + ct * TBN;
    f32x4 acc[2][4];
#pragma unroll
    for (int m = 0; m < 2; ++m)
#pragma unroll
      for (int n = 0; n < 4; ++n) acc[m][n] = (f32x4){0.f, 0.f, 0.f, 0.f};

    for (int kt = 0; kt < Dk / BK; ++kt) {
      const int s = ct * 8 + kt;
      __syncthreads();  // drains stage(s) (issued a full compute phase ago) + publishes
      if (s + 1 < NSTEP) stage(s + 1);
      if (s == 0) {  // labels now visible
#pragma unroll
        for (int m = 0; m < 2; ++m)
#pragma unroll
          for (int r = 0; r < 4; ++r) rlab[m][r] = rl[rowl[m][r]];
      }
      const int bb = s & 1;
#pragma unroll
      for (int ks = 0; ks < 2; ++ks) {
        const int kb = ks * 4 + l4;
        bf16x8 af[2], bf[4];
#pragma unroll
        for (int m = 0; m < 2; ++m)
          af[m] = *(const bf16x8*)&As[bb][(kb * 128 + WR * 32 + m * 16 + l15) * 8];
#pragma unroll
        for (int n = 0; n < 4; ++n)
          bf[n] = *(const bf16x8*)&Bs[bb][(kb * 128 + WC * 64 + n * 16 + l15) * 8];
#pragma unroll
        for (int m = 0; m < 2; ++m)
#pragma unroll
          for (int n = 0; n < 4; ++n)
            acc[m][n] = __builtin_amdgcn_mfma_f32_16x16x32_bf16(af[m], bf[n], acc[m][n], 0, 0, 0);
      }
    }

    // ---- fold this 128x128 tile into per-lane row stats (+ optional sim write) ----
    const bool diag = (col0 == row0);
#pragma unroll
    for (int n = 0; n < 4; ++n) {
      const int lcolt = WC * 64 + n * 16 + l15;            // tile-local col
      const int clab = cl[ct * TBN + lcolt];
#pragma unroll
      for (int m = 0; m < 2; ++m) {
        float tv[4];
#pragma unroll
        for (int r = 0; r < 4; ++r) {
          float s = acc[m][n][r];
          if (diag && (lcolt == rowl[m][r])) s = 1.0f;  // exact self-sim
          tv[r] = s;
        }
        if constexpr (WSIM) {
          u16x4 w;
#pragma unroll
          for (int r = 0; r < 4; ++r) w[r] = f2bf(tv[r]);
          // simb[c][r]: by symmetry this is sim row c. 4 consecutive rows -> 8B store.
          *(u16x4*)(simb + (size_t)(col0 + lcolt) * Bn +
                    (row0 + WR * 32 + m * 16 + l4 * 4)) = w;
        }
#pragma unroll
        for (int r = 0; r < 4; ++r) {
          float s = tv[r];
          bool same = (rlab[m][r] == clab);
          if constexpr (PHASE == 1) {
            s0[m][r] += s;
            s1[m][r] += s * s;
            if (!same) s2[m][r] = fmaxf(s2[m][r], s);
            else if (s < ONE_EPS) { s3[m][r] = fminf(s3[m][r], s); s4[m][r] += 1.0f; }
          } else {
            bool psel = same && (s < ONE_EPS) && (s - 0.1f < thrp[m][r]);
            bool nsel = (!same) && (s + 0.1f > thrn[m][r]);
            if (psel) { s0[m][r] += 1.0f; s4[m][r] += __expf(2.0f - 2.0f * s); }
            if (nsel) { s1[m][r] += 1.0f; s5[m][r] += __expf(2.0f * s - 1.2f); }
            if (psel || nsel) { s2[m][r] += s; s3[m][r] += s * s; }
          }
        }
      }
    }
  }

  // butterfly across the 16 lanes holding different cols of the same rows
#pragma unroll
  for (int d = 1; d < 16; d <<= 1) {
#pragma unroll
    for (int m = 0; m < 2; ++m)
#pragma unroll
      for (int r = 0; r < 4; ++r) {
        s0[m][r] += __shfl_xor(s0[m][r], d);
        s1[m][r] += __shfl_xor(s1[m][r], d);
        if constexpr (PHASE == 1) {
          s2[m][r] = fmaxf(s2[m][r], __shfl_xor(s2[m][r], d));
          s3[m][r] = fminf(s3[m][r], __shfl_xor(s3[m][r], d));
          s4[m][r] += __shfl_xor(s4[m][r], d);
        } else {
          s2[m][r] += __shfl_xor(s2[m][r], d);
          s3[m][r] += __shfl_xor(s3[m][r], d);
          s4[m][r] += __shfl_xor(s4[m][r], d);
          s5[m][r] += __shfl_xor(s5[m][r], d);
        }
      }
  }

  // ---- merge the two WC halves in LDS, then one write per row per block ----
  __syncthreads();  // all compute done; reuse As as float scratch
  float* mbuf = (float*)&As[0][0];  // BM*6 floats = 3 KB
  if (WC == 1 && l15 == 0) {
#pragma unroll
    for (int m = 0; m < 2; ++m)
#pragma unroll
      for (int r = 0; r < 4; ++r) {
        int lr = rowl[m][r];
        mbuf[lr * 6 + 0] = s0[m][r];
        mbuf[lr * 6 + 1] = s1[m][r];
        mbuf[lr * 6 + 2] = s2[m][r];
        mbuf[lr * 6 + 3] = s3[m][r];
        mbuf[lr * 6 + 4] = s4[m][r];
        mbuf[lr * 6 + 5] = s5[m][r];
      }
  }
  __syncthreads();
  if (WC == 0 && l15 == 0) {
    const int slot = blockIdx.y;  // 16 slots per row
#pragma unroll
    for (int m = 0; m < 2; ++m)
#pragma unroll
      for (int r = 0; r < 4; ++r) {
        int lr = rowl[m][r];
        int rowg = row0 + lr;
        const float* p = &mbuf[lr * 6];
        float t0 = s0[m][r] + p[0];
        float t1 = s1[m][r] + p[1];
        float t2, t3;
        if constexpr (PHASE == 1) {
          t2 = fmaxf(s2[m][r], p[2]);
          t3 = fminf(s3[m][r], p[3]);
        } else {
          t2 = s2[m][r] + p[2];
          t3 = s3[m][r] + p[3];
        }
        float t4 = s4[m][r] + p[4];
        part[(size_t)(0 * Bn + rowg) * 16 + slot] = t0;
        part[(size_t)(1 * Bn + rowg) * 16 + slot] = t1;
        part[(size_t)(2 * Bn + rowg) * 16 + slot] = t2;
        part[(size_t)(3 * Bn + rowg) * 16 + slot] = t3;
        part[(size_t)(4 * Bn + rowg) * 16 + slot] = t4;
        if constexpr (PHASE == 2)
          part[(size_t)(5 * Bn + rowg) * 16 + slot] = s5[m][r] + p[5];
      }
  }
}

// ---- Path A pass 2: one wave per row; fuses slot-reduce + stream-fold + finalize ----
__global__ __launch_bounds__(512) void pass2_kernel(const unsigned short* __restrict__ simb,
                                                    const int* __restrict__ labels,
                                                    const float* __restrict__ p1,
                                                    float* __restrict__ out) {
  __shared__ int cl[Bn];      // all 4096 labels, 16KB
  __shared__ float bs[8];
  const int tid = threadIdx.x;
  for (int i = tid; i < Bn / 4; i += 512) ((int4*)cl)[i] = ((const int4*)labels)[i];
  __syncthreads();
  const int lane = tid & 63;
  const int wv = tid >> 6;
  const int row = blockIdx.x * 8 + wv;
  const int rlab = cl[row];

  // pass-1 slot reduce (16 slots, lanes duplicate in 16-groups)
  const int sl = lane & 15;
  float ssum = p1[(size_t)(0 * Bn + row) * 16 + sl];
  float sssq = p1[(size_t)(1 * Bn + row) * 16 + sl];
  float smxn = p1[(size_t)(2 * Bn + row) * 16 + sl];
  float smnp = p1[(size_t)(3 * Bn + row) * 16 + sl];
  float spc  = p1[(size_t)(4 * Bn + row) * 16 + sl];
#pragma unroll
  for (int d = 1; d < 16; d <<= 1) {
    ssum += __shfl_xor(ssum, d);
    sssq += __shfl_xor(sssq, d);
    smxn = fmaxf(smxn, __shfl_xor(smxn, d));
    smnp = fminf(smnp, __shfl_xor(smnp, d));
    spc += __shfl_xor(spc, d);
  }
  const float thrp = smxn;  // max_neg
  const float thrn = smnp;  // min_pos

  float np = 0.f, nn = 0.f, ssel = 0.f, qsel = 0.f, fp = 0.f, fn = 0.f;
  const unsigned short* rp = simb + (size_t)row * Bn;
#pragma unroll
  for (int it = 0; it < 8; ++it) {
    const int base = it * 512 + lane * 8;
    bf16x8 v = *(const bf16x8*)(rp + base);
    int4 la = *(const int4*)&cl[base];
    int4 lb = *(const int4*)&cl[base + 4];
    int lv[8] = {la.x, la.y, la.z, la.w, lb.x, lb.y, lb.z, lb.w};
#pragma unroll
    for (int e = 0; e < 8; ++e) {
      float s = __uint_as_float(((unsigned int)(unsigned short)v[e]) << 16);
      bool same = (lv[e] == rlab);
      bool psel = same && (s < ONE_EPS) && (s - 0.1f < thrp);
      bool nsel = (!same) && (s + 0.1f > thrn);
      if (psel) { np += 1.f; fp += __expf(2.0f - 2.0f * s); }
      if (nsel) { nn += 1.f; fn += __expf(2.0f * s - 1.2f); }
      if (psel || nsel) { ssel += s; qsel += s * s; }
    }
  }
#pragma unroll
  for (int d = 1; d < 64; d <<= 1) {
    np += __shfl_xor(np, d); nn += __shfl_xor(nn, d);
    ssel += __shfl_xor(ssel, d); qsel += __shfl_xor(qsel, d);
    fp += __shfl_xor(fp, d); fn += __shfl_xor(fn, d);
  }

  float mean_all = ssum * (1.0f / Bn);
  float sigma_all = sssq - (float)Bn * mean_all * mean_all;
  float cnt = fmaxf(np + nn, 1.0f);
  float mean_sel = ssel / cnt;
  float sigma_sel = qsel / cnt - mean_sel * mean_sel;
  float loss = __logf(1.0f + fp) + __logf(1.0f + fn) +
               0.5f * (fabsf(mean_all - mean_sel) + fabsf(sigma_all - sigma_sel));
  bool valid = (spc > 0.5f) && (spc < (float)(Bn - 1) - 0.5f) && (np > 0.5f) && (nn > 0.5f);
  float v0 = valid ? loss : 0.f;

  if (lane == 0) bs[wv] = v0;
  __syncthreads();
  if (tid == 0) {
    float t = bs[0] + bs[1] + bs[2] + bs[3] + bs[4] + bs[5] + bs[6] + bs[7];
    atomicAdd(out, t * (1.0f / (float)Bn));
  }
}

// ---- Path B (fallback) helpers: round-4 verified ----
__global__ __launch_bounds__(256) void reduce1_kernel(const float* __restrict__ part,
                                                      float* __restrict__ rs) {
  int row = blockIdx.x * 256 + threadIdx.x;
  float sum = 0.f, ssq = 0.f, pc = 0.f;
  float mxn = -__builtin_inff(), mnp = __builtin_inff();
#pragma unroll
  for (int sl = 0; sl < 16; ++sl) {
    sum += part[(size_t)(0 * Bn + row) * 16 + sl];
    ssq += part[(size_t)(1 * Bn + row) * 16 + sl];
    mxn = fmaxf(mxn, part[(size_t)(2 * Bn + row) * 16 + sl]);
    mnp = fminf(mnp, part[(size_t)(3 * Bn + row) * 16 + sl]);
    pc += part[(size_t)(4 * Bn + row) * 16 + sl];
  }
  rs[0 * Bn + row] = sum;
  rs[1 * Bn + row] = ssq;
  rs[2 * Bn + row] = mxn;
  rs[3 * Bn + row] = mnp;
  rs[4 * Bn + row] = pc;
}

__global__ __launch_bounds__(256) void finalize_kernel(const float* __restrict__ p2,
                                                       const float* __restrict__ rs,
                                                       float* __restrict__ out) {
  int tid = threadIdx.x;
  int row = blockIdx.x * 256 + tid;
  float np = 0.f, nn = 0.f, ssel = 0.f, qsel = 0.f, fp = 0.f, fn = 0.f;
#pragma unroll
  for (int sl = 0; sl < 16; ++sl) {
    np += p2[(size_t)(0 * Bn + row) * 16 + sl];
    nn += p2[(size_t)(1 * Bn + row) * 16 + sl];
    ssel += p2[(size_t)(2 * Bn + row) * 16 + sl];
    qsel += p2[(size_t)(3 * Bn + row) * 16 + sl];
    fp += p2[(size_t)(4 * Bn + row) * 16 + sl];
    fn += p2[(size_t)(5 * Bn + row) * 16 + sl];
  }
  float sumall = rs[0 * Bn + row];
  float ssqall = rs[1 * Bn + row];
  float pc = rs[4 * Bn + row];

  float mean_all = sumall * (1.0f / Bn);
  float sigma_all = ssqall - (float)Bn * mean_all * mean_all;
  float cnt = fmaxf(np + nn, 1.0f);
  float mean_sel = ssel / cnt;
  float sigma_sel = qsel / cnt - mean_sel * mean_sel;
  float loss = __logf(1.0f + fp) + __logf(1.0f + fn) +
               0.5f * (fabsf(mean_all - mean_sel) + fabsf(sigma_all - sigma_sel));
  bool valid = (pc > 0.5f) && (pc < (float)(Bn - 1) - 0.5f) && (np > 0.5f) && (nn > 0.5f);
  float v = valid ? loss : 0.f;
#pragma unroll
  for (int d = 1; d < 64; d <<= 1) v += __shfl_xor(v, d);
  __shared__ float ls[4];
  if ((tid & 63) == 0) ls[tid >> 6] = v;
  __syncthreads();
  if (tid == 0) atomicAdd(out, (ls[0] + ls[1] + ls[2] + ls[3]) * (1.0f / (float)Bn));
}

extern "C" void kernel_launch(void* const* d_in, const int* in_sizes, int n_in,
                              void* d_out, int out_size, void* d_ws, size_t ws_size,
                              hipStream_t stream) {
  const float* feats = (const float*)d_in[0];
  const int* labels = (const int*)d_in[1];
  float* out = (float*)d_out;
  char* ws = (char*)d_ws;

  unsigned short* featT = (unsigned short*)ws;                      // 4,194,304
  float* p1 = (float*)(ws + 4194304);                               // 5*4096*16*4 = 1,310,720
  const size_t needA = 4194304ull + 1310720ull + 33554432ull;       // + simb 32MB

  hipMemsetAsync(d_out, 0, sizeof(float), stream);
  convert_kernel<<<1024, 256, 0, stream>>>(feats, featT);
  dim3 g(Bn / BM, NCHUNK);

  if (ws_size >= needA) {
    // Path A: single GEMM with sim materialization, then streaming pass 2.
    unsigned short* simb = (unsigned short*)(ws + 4194304 + 1310720);
    phase_kernel<1, true><<<g, 512, 0, stream>>>(featT, labels, nullptr, p1, simb);
    pass2_kernel<<<512, 512, 0, stream>>>(simb, labels, p1, out);
  } else {
    // Path B: round-4 verified two-GEMM structure.
    float* rs = (float*)(ws + 4194304 + 1310720);                   // 81,920
    float* p2 = (float*)(ws + 4194304 + 1310720 + 81920);           // 1,572,864
    phase_kernel<1, false><<<g, 512, 0, stream>>>(featT, labels, nullptr, p1, nullptr);
    reduce1_kernel<<<Bn / 256, 256, 0, stream>>>(p1, rs);
    phase_kernel<2, false><<<g, 512, 0, stream>>>(featT, labels, rs, p2, nullptr);
    finalize_kernel<<<Bn / 256, 256, 0, stream>>>(p2, rs, out);
  }
}